// Round 4
// baseline (248.300 us; speedup 1.0000x reference)
//
#include <hip/hip_runtime.h>

#define CH    1024
#define NST   16
#define BSZ   16
#define LSEQ  4096
#define T     64                 // chunk length; lane m scans chunk m
#define CN    (CH * NST)         // 16384
#define PADW  65                 // padded LDS row stride in dwords

// ws layout (floats): [0,CN) lam_r  [CN,2CN) lam_i  [2CN,3CN) e_hat
//                     [3CN,4CN) q_r (=lam^64 real)  [4CN,5CN) q_i

__global__ void setup_k(const float* __restrict__ A, const float* __restrict__ log_dt,
                        const float* __restrict__ E, float* __restrict__ ws) {
    int i = blockIdx.x * 256 + threadIdx.x;
    if (i >= CN) return;
    float a0 = A[2 * i], a1 = A[2 * i + 1];
    float sp = (a0 > 20.f) ? a0 : log1pf(expf(a0));   // softplus
    float dt = expf(log_dt[i]);
    float eh = E[i] * dt;
    float dar = -dt * sp;
    float dai = dt * a1;
    float mag = expf(dar);
    float s1, c1;
    sincosf(dai, &s1, &c1);
    ws[i]          = mag * c1;   // lam_r
    ws[CN + i]     = mag * s1;   // lam_i
    ws[2 * CN + i] = eh;
    float magT = expf(dar * (float)T);
    float sT, cT;
    sincosf(dai * (float)T, &sT, &cT);
    ws[3 * CN + i] = magT * cT;  // q_r
    ws[4 * CN + i] = magT * sT;  // q_i
}

// pack two floats to bf16 pair (RNE), low = a, high = b
__device__ __forceinline__ unsigned int pk2(float a, float b) {
    unsigned int ua = __float_as_uint(a);
    unsigned int ub = __float_as_uint(b);
    ua = (ua + 0x7fffu + ((ua >> 16) & 1u)) >> 16;
    ub = (ub + 0x7fffu + ((ub >> 16) & 1u)) & 0xffff0000u;
    return ua | ub;
}
__device__ __forceinline__ float lo2(unsigned int w) { return __uint_as_float(w << 16); }
__device__ __forceinline__ float hi2(unsigned int w) { return __uint_as_float(w & 0xffff0000u); }

__global__ __launch_bounds__(64, 4) void scan_k(const float* __restrict__ x,
                                                const float* __restrict__ ws,
                                                float* __restrict__ y) {
    __shared__ unsigned int lds[32 * PADW];  // lds[j2*PADW + m] = bf16 pair x[m*64+2*j2], x[m*64+2*j2+1]
    const int lane = threadIdx.x;            // 0..63 = chunk index m
    const int row  = blockIdx.x;             // b*CH + c
    const int c    = row & (CH - 1);
    const float* xr = x + (size_t)row * LSEQ;
    float*       yr = y + (size_t)row * LSEQ;

    const int m_hi  = lane >> 4;             // row offset within 4-group
    const int j2_st = 2 * (lane & 15);

    // ---- stage x -> LDS (transposed, bf16-packed), fully coalesced reads ----
#pragma unroll
    for (int r = 0; r < 16; ++r) {
        float4 v = *(const float4*)(xr + 256 * r + 4 * lane);
        int m = 4 * r + m_hi;
        lds[j2_st * PADW + m]       = pk2(v.x, v.y);
        lds[(j2_st + 1) * PADW + m] = pk2(v.z, v.w);
    }
    __syncthreads();

    // ---- params ----
    float lr[NST], li[NST];
#pragma unroll
    for (int n = 0; n < NST; ++n) {
        lr[n] = ws[c * NST + n];
        li[n] = ws[CN + c * NST + n];
    }

    // ---- pass 1: local chunk scan from zero ----
    float sr[NST], si[NST];
#pragma unroll
    for (int n = 0; n < NST; ++n) { sr[n] = 0.f; si[n] = 0.f; }
#pragma unroll 4
    for (int j2 = 0; j2 < 32; ++j2) {
        unsigned int w = lds[j2 * PADW + lane];
        float x0 = lo2(w), x1 = hi2(w);
#pragma unroll
        for (int n = 0; n < NST; ++n) {
            float srn = fmaf(lr[n], sr[n], fmaf(-li[n], si[n], x0));
            si[n] = fmaf(lr[n], si[n], li[n] * sr[n]);
            sr[n] = srn;
        }
#pragma unroll
        for (int n = 0; n < NST; ++n) {
            float srn = fmaf(lr[n], sr[n], fmaf(-li[n], si[n], x1));
            si[n] = fmaf(lr[n], si[n], li[n] * sr[n]);
            sr[n] = srn;
        }
    }

    // ---- wave-level combine: inclusive scan with ratio q = lam^64 ----
    {
        float pqr[NST], pqi[NST];
#pragma unroll
        for (int n = 0; n < NST; ++n) {
            pqr[n] = ws[3 * CN + c * NST + n];
            pqi[n] = ws[4 * CN + c * NST + n];
        }
#pragma unroll
        for (int d = 1; d < 64; d <<= 1) {
#pragma unroll
            for (int n = 0; n < NST; ++n) {
                float ur = __shfl_up(sr[n], d);
                float ui = __shfl_up(si[n], d);
                ur = (lane >= d) ? ur : 0.f;
                ui = (lane >= d) ? ui : 0.f;
                sr[n] = fmaf(pqr[n], ur, fmaf(-pqi[n], ui, sr[n]));
                si[n] = fmaf(pqr[n], ui, fmaf(pqi[n], ur, si[n]));
            }
#pragma unroll
            for (int n = 0; n < NST; ++n) {       // q <- q^2
                float t = fmaf(pqr[n], pqr[n], -(pqi[n] * pqi[n]));
                pqi[n] = 2.f * pqr[n] * pqi[n];
                pqr[n] = t;
            }
        }
        // S_in[m] = A[m-1], zero for m=0
#pragma unroll
        for (int n = 0; n < NST; ++n) {
            float ar = __shfl_up(sr[n], 1);
            float ai = __shfl_up(si[n], 1);
            sr[n] = (lane > 0) ? ar : 0.f;
            si[n] = (lane > 0) ? ai : 0.f;
        }
    }

    // ---- pass 2: re-scan with incoming state, emit y (bf16-packed) in place ----
    float eh[NST];
#pragma unroll
    for (int n = 0; n < NST; ++n) eh[n] = ws[2 * CN + c * NST + n];
#pragma unroll 4
    for (int j2 = 0; j2 < 32; ++j2) {
        unsigned int w = lds[j2 * PADW + lane];
        float x0 = lo2(w), x1 = hi2(w);
        float a0 = 0.f, a1 = 0.f;
#pragma unroll
        for (int n = 0; n < NST; ++n) {
            float srn = fmaf(lr[n], sr[n], fmaf(-li[n], si[n], x0));
            si[n] = fmaf(lr[n], si[n], li[n] * sr[n]);
            sr[n] = srn;
            if (n & 1) a1 = fmaf(eh[n], srn, a1);
            else       a0 = fmaf(eh[n], srn, a0);
        }
        float y0 = a0 + a1;
        float b0 = 0.f, b1 = 0.f;
#pragma unroll
        for (int n = 0; n < NST; ++n) {
            float srn = fmaf(lr[n], sr[n], fmaf(-li[n], si[n], x1));
            si[n] = fmaf(lr[n], si[n], li[n] * sr[n]);
            sr[n] = srn;
            if (n & 1) b1 = fmaf(eh[n], srn, b1);
            else       b0 = fmaf(eh[n], srn, b0);
        }
        float y1 = b0 + b1;
        lds[j2 * PADW + lane] = pk2(y0, y1);
    }
    __syncthreads();

    // ---- store y out (transposed back), fully coalesced ----
#pragma unroll
    for (int r = 0; r < 16; ++r) {
        int m = 4 * r + m_hi;
        unsigned int w0 = lds[j2_st * PADW + m];
        unsigned int w1 = lds[(j2_st + 1) * PADW + m];
        float4 v;
        v.x = lo2(w0); v.y = hi2(w0); v.z = lo2(w1); v.w = hi2(w1);
        *(float4*)(yr + 256 * r + 4 * lane) = v;
    }
}

extern "C" void kernel_launch(void* const* d_in, const int* in_sizes, int n_in,
                              void* d_out, int out_size, void* d_ws, size_t ws_size,
                              hipStream_t stream) {
    const float* x      = (const float*)d_in[0];
    const float* A      = (const float*)d_in[1];
    const float* log_dt = (const float*)d_in[4];
    const float* E      = (const float*)d_in[5];
    float* out = (float*)d_out;
    float* ws  = (float*)d_ws;

    setup_k<<<CN / 256, 256, 0, stream>>>(A, log_dt, E, ws);
    scan_k<<<BSZ * CH, 64, 0, stream>>>(x, ws, out);
}

// Round 5
// 142.431 us; speedup vs baseline: 1.7433x; 1.7433x over previous
//
#include <hip/hip_runtime.h>

#define CH   1024
#define BSZ  16
#define LSEQ 4096
#define NST  16

typedef __attribute__((ext_vector_type(8))) short short8;
typedef __attribute__((ext_vector_type(4))) float f32x4;

// pack two floats to bf16 pair (RNE), low = a, high = b
__device__ __forceinline__ unsigned int pk2(float a, float b) {
    unsigned int ua = __float_as_uint(a);
    unsigned int ub = __float_as_uint(b);
    ua = (ua + 0x7fffu + ((ua >> 16) & 1u)) >> 16;
    ub = (ub + 0x7fffu + ((ub >> 16) & 1u)) & 0xffff0000u;
    return ua | ub;
}

// ws byte layout:
//   P: [c][64 rows i][96 cols k] bf16   (K Toeplitz | D inject)   12,582,912 B
//   W: [c][32 rows p][64 cols j] bf16   (state extraction)         4,194,304 B
//   q: [c][32] f32   (lam^64 re,im interleaved)                      131,072 B
#define P_BYTES 12582912
#define W_BYTES 4194304

__global__ __launch_bounds__(64) void setup_k(const float* __restrict__ A,
                                              const float* __restrict__ log_dt,
                                              const float* __restrict__ E,
                                              unsigned int* __restrict__ Pw,
                                              unsigned int* __restrict__ Ww,
                                              float* __restrict__ qw) {
    __shared__ float powr[NST][65], powi[NST][65], eh[NST], klds[64];
    const int t = threadIdx.x, c = blockIdx.x;
    const int n = t & 15;
    const int idx = c * NST + n;
    float a0 = A[2 * idx], a1 = A[2 * idx + 1];
    float sp = (a0 > 20.f) ? a0 : log1pf(expf(a0));   // softplus
    float dt = expf(log_dt[idx]);
    float dar = -dt * sp, dai = dt * a1;
    float ehv = E[idx] * dt;
    if (t < NST) eh[t] = ehv;
    for (int l = t >> 4; l < 65; l += 4) {
        float mg = expf(dar * (float)l);
        float s, cs;
        sincosf(dai * (float)l, &s, &cs);
        powr[n][l] = mg * cs;
        powi[n][l] = mg * s;
    }
    __syncthreads();
    float kl = 0.f;
#pragma unroll
    for (int nn = 0; nn < NST; ++nn) kl += eh[nn] * powr[nn][t];
    klds[t] = kl;
    __syncthreads();
    // P rows: 96 bf16 = 48 dwords; 3072 dwords total, coalesced dword writes
    unsigned int* Pc = Pw + c * 3072;
    for (int kk = 0; kk < 48; ++kk) {
        int d = kk * 64 + t;
        int i = d / 48;
        int k0 = (d - i * 48) * 2;
        float vv[2];
#pragma unroll
        for (int u = 0; u < 2; ++u) {
            int k = k0 + u;
            if (k < 64) vv[u] = (k <= i) ? klds[i - k] : 0.f;
            else {
                int p = k - 64;
                int nn = p >> 1;
                vv[u] = (p & 1) ? (-eh[nn] * powi[nn][i + 1]) : (eh[nn] * powr[nn][i + 1]);
            }
        }
        Pc[d] = pk2(vv[0], vv[1]);
    }
    // W rows: 64 bf16 = 32 dwords; 1024 dwords
    unsigned int* Wc = Ww + c * 1024;
    for (int kk = 0; kk < 16; ++kk) {
        int d = kk * 64 + t;
        int p = d >> 5;
        int j0 = (d & 31) * 2;
        int nn = p >> 1;
        float v0 = (p & 1) ? powi[nn][63 - j0] : powr[nn][63 - j0];
        float v1 = (p & 1) ? powi[nn][62 - j0] : powr[nn][62 - j0];
        Wc[d] = pk2(v0, v1);
    }
    if (t < 32) qw[c * 32 + t] = (t & 1) ? powi[t >> 1][64] : powr[t >> 1][64];
}

// LDS: XT (bf16, swizzled) 8192 | S f32 [32][65] 8320 | SinT bf16 swizzled 4096
#define XT_OFF  0
#define S_OFF   8192
#define SIN_OFF 16512
#define SMEM_SZ 20608

__global__ __launch_bounds__(256) void conv_k(const float* __restrict__ x,
                                              const char* __restrict__ Pb,
                                              const char* __restrict__ Wb,
                                              const float* __restrict__ qw,
                                              float* __restrict__ y) {
    __shared__ __align__(16) char smem[SMEM_SZ];
    const int tid  = threadIdx.x;
    const int w    = tid >> 6, lane = tid & 63;
    const int g    = lane >> 4, l15 = lane & 15;
    const int bid  = blockIdx.x;
    const int c    = bid & (CH - 1);
    const int b    = bid >> 10;
    const size_t rowoff = ((size_t)(b * CH + c)) * LSEQ;
    const float* xr = x + rowoff;
    float*       yr = y + rowoff;

    // ---- prefetch A-fragments + q (L2-resident per XCD) ----
    const char* Pc = Pb + (size_t)c * 12288;
    const char* Wc = Wb + (size_t)c * 4096;
    short8 wa[2], pa[3];
    {
        int p = 16 * (w >> 1) + l15;
#pragma unroll
        for (int kt = 0; kt < 2; ++kt)
            wa[kt] = *(const short8*)(Wc + p * 128 + kt * 64 + g * 16);
        int i = 16 * w + l15;
#pragma unroll
        for (int kt = 0; kt < 3; ++kt)
            pa[kt] = *(const short8*)(Pc + i * 192 + kt * 64 + g * 16);
    }
    float qr[4], qi[4];
#pragma unroll
    for (int k = 0; k < 4; ++k) {
        int nn = 4 * w + k;
        qr[k] = qw[c * 32 + 2 * nn];
        qi[k] = qw[c * 32 + 2 * nn + 1];
    }

    // ---- stage x -> XT bf16 (transposed to [chunk m][j], XOR-swizzled) ----
#pragma unroll
    for (int it = 0; it < 4; ++it) {
        float4 v = *(const float4*)(xr + 1024 * it + 4 * tid);
        int m = 16 * it + (tid >> 4);
        int byte = (m * 128 + 8 * (tid & 15)) ^ ((m & 7) << 4);
        *(uint2*)(smem + XT_OFF + byte) = make_uint2(pk2(v.x, v.y), pk2(v.z, v.w));
    }
    __syncthreads();

    // ---- GEMM1: S(32x64) = W @ X ----
    {
        f32x4 acc[2] = {{0.f, 0.f, 0.f, 0.f}, {0.f, 0.f, 0.f, 0.f}};
        int ntb = 2 * (w & 1);
#pragma unroll
        for (int nt = 0; nt < 2; ++nt) {
            int m = l15 + 16 * (ntb + nt);
            int sw = (m & 7) << 4;
#pragma unroll
            for (int kt = 0; kt < 2; ++kt) {
                short8 bf = *(const short8*)(smem + XT_OFF + ((m * 128 + kt * 64 + g * 16) ^ sw));
                acc[nt] = __builtin_amdgcn_mfma_f32_16x16x32_bf16(wa[kt], bf, acc[nt], 0, 0, 0);
            }
        }
        float* S = (float*)(smem + S_OFF);
        int pbase = 16 * (w >> 1) + 4 * g;
#pragma unroll
        for (int nt = 0; nt < 2; ++nt) {
            int m = l15 + 16 * (ntb + nt);
#pragma unroll
            for (int r = 0; r < 4; ++r)
                S[(pbase + r) * 65 + m] = acc[nt][r];
        }
    }
    __syncthreads();

    // ---- chunk scan: wave w owns n = 4w..4w+3, lane = chunk m ----
    {
        const float* S = (const float*)(smem + S_OFF);
        float sr[4], si[4];
#pragma unroll
        for (int k = 0; k < 4; ++k) {
            int nn = 4 * w + k;
            sr[k] = S[(2 * nn) * 65 + lane];
            si[k] = S[(2 * nn + 1) * 65 + lane];
        }
#pragma unroll
        for (int d = 1; d < 64; d <<= 1) {
#pragma unroll
            for (int k = 0; k < 4; ++k) {
                float ur = __shfl_up(sr[k], d);
                float ui = __shfl_up(si[k], d);
                ur = (lane >= d) ? ur : 0.f;
                ui = (lane >= d) ? ui : 0.f;
                sr[k] = fmaf(qr[k], ur, fmaf(-qi[k], ui, sr[k]));
                si[k] = fmaf(qr[k], ui, fmaf(qi[k], ur, si[k]));
            }
#pragma unroll
            for (int k = 0; k < 4; ++k) {   // q <- q^2
                float tq = fmaf(qr[k], qr[k], -(qi[k] * qi[k]));
                qi[k] = 2.f * qr[k] * qi[k];
                qr[k] = tq;
            }
        }
        unsigned int dw[4];
#pragma unroll
        for (int k = 0; k < 4; ++k) {       // exclusive shift: S_in[m] = A[m-1]
            float ar = __shfl_up(sr[k], 1);
            float ai = __shfl_up(si[k], 1);
            ar = (lane > 0) ? ar : 0.f;
            ai = (lane > 0) ? ai : 0.f;
            dw[k] = pk2(ar, ai);
        }
        int byte = (lane * 64 + 16 * w) ^ ((lane & 3) << 4);
        *(uint4*)(smem + SIN_OFF + byte) = make_uint4(dw[0], dw[1], dw[2], dw[3]);
    }
    __syncthreads();

    // ---- GEMM2: Y(64x64) = P(64x96) @ [X; S_in](96x64) ----
    {
        f32x4 acc[4] = {{0.f,0.f,0.f,0.f},{0.f,0.f,0.f,0.f},{0.f,0.f,0.f,0.f},{0.f,0.f,0.f,0.f}};
#pragma unroll
        for (int nt = 0; nt < 4; ++nt) {
            int m = l15 + 16 * nt;
            int sw = (m & 7) << 4;
#pragma unroll
            for (int kt = 0; kt < 2; ++kt) {
                short8 bf = *(const short8*)(smem + XT_OFF + ((m * 128 + kt * 64 + g * 16) ^ sw));
                acc[nt] = __builtin_amdgcn_mfma_f32_16x16x32_bf16(pa[kt], bf, acc[nt], 0, 0, 0);
            }
            short8 sf = *(const short8*)(smem + SIN_OFF + ((m * 64 + g * 16) ^ ((m & 3) << 4)));
            acc[nt] = __builtin_amdgcn_mfma_f32_16x16x32_bf16(pa[2], sf, acc[nt], 0, 0, 0);
        }
        // lane holds col m, rows i0..i0+3, i0 = 16w + 4g -> contiguous float4 in y
#pragma unroll
        for (int nt = 0; nt < 4; ++nt) {
            int m = l15 + 16 * nt;
            float4 v = make_float4(acc[nt][0], acc[nt][1], acc[nt][2], acc[nt][3]);
            *(float4*)(yr + m * 64 + 16 * w + 4 * g) = v;
        }
    }
}

extern "C" void kernel_launch(void* const* d_in, const int* in_sizes, int n_in,
                              void* d_out, int out_size, void* d_ws, size_t ws_size,
                              hipStream_t stream) {
    const float* x      = (const float*)d_in[0];
    const float* A      = (const float*)d_in[1];
    const float* log_dt = (const float*)d_in[4];
    const float* E      = (const float*)d_in[5];
    float* out = (float*)d_out;
    char*  ws  = (char*)d_ws;

    unsigned int* Pw = (unsigned int*)ws;
    unsigned int* Ww = (unsigned int*)(ws + P_BYTES);
    float*        qw = (float*)(ws + P_BYTES + W_BYTES);

    setup_k<<<CH, 64, 0, stream>>>(A, log_dt, E, Pw, Ww, qw);
    conv_k<<<BSZ * CH, 256, 0, stream>>>(x, (const char*)Pw, (const char*)Ww, qw, out);
}

// Round 6
// 131.734 us; speedup vs baseline: 1.8849x; 1.0812x over previous
//
#include <hip/hip_runtime.h>

#define CH   1024
#define BSZ  16
#define LSEQ 4096
#define NST  16

typedef __attribute__((ext_vector_type(8))) short short8;
typedef __attribute__((ext_vector_type(4))) float f32x4;

// pack two floats to bf16 pair (RNE), low = a, high = b
__device__ __forceinline__ unsigned int pk2(float a, float b) {
    unsigned int ua = __float_as_uint(a);
    unsigned int ub = __float_as_uint(b);
    ua = (ua + 0x7fffu + ((ua >> 16) & 1u)) >> 16;
    ub = (ub + 0x7fffu + ((ub >> 16) & 1u)) & 0xffff0000u;
    return ua | ub;
}

// ws byte layout:
//   P: [c][64 rows i][96 cols k] bf16   (K Toeplitz | D inject)   12,582,912 B
//   W: [c][32 rows p][64 cols j] bf16   (state extraction)         4,194,304 B
//   q: [c][32] f32   (lam^64 re,im interleaved)                      131,072 B
#define P_BYTES 12582912
#define W_BYTES 4194304

__global__ __launch_bounds__(64) void setup_k(const float* __restrict__ A,
                                              const float* __restrict__ log_dt,
                                              const float* __restrict__ E,
                                              unsigned int* __restrict__ Pw,
                                              unsigned int* __restrict__ Ww,
                                              float* __restrict__ qw) {
    __shared__ float powr[NST][65], powi[NST][65], eh[NST], klds[64];
    const int t = threadIdx.x, c = blockIdx.x;
    const int n = t & 15;
    const int idx = c * NST + n;
    float a0 = A[2 * idx], a1 = A[2 * idx + 1];
    float sp = (a0 > 20.f) ? a0 : log1pf(expf(a0));   // softplus
    float dt = expf(log_dt[idx]);
    float dar = -dt * sp, dai = dt * a1;
    float ehv = E[idx] * dt;
    if (t < NST) eh[t] = ehv;
    for (int l = t >> 4; l < 65; l += 4) {
        float mg = expf(dar * (float)l);
        float s, cs;
        sincosf(dai * (float)l, &s, &cs);
        powr[n][l] = mg * cs;
        powi[n][l] = mg * s;
    }
    __syncthreads();
    float kl = 0.f;
#pragma unroll
    for (int nn = 0; nn < NST; ++nn) kl += eh[nn] * powr[nn][t];
    klds[t] = kl;
    __syncthreads();
    // P rows: 96 bf16 = 48 dwords; 3072 dwords total, coalesced dword writes
    unsigned int* Pc = Pw + c * 3072;
    for (int kk = 0; kk < 48; ++kk) {
        int d = kk * 64 + t;
        int i = d / 48;
        int k0 = (d - i * 48) * 2;
        float vv[2];
#pragma unroll
        for (int u = 0; u < 2; ++u) {
            int k = k0 + u;
            if (k < 64) vv[u] = (k <= i) ? klds[i - k] : 0.f;
            else {
                int p = k - 64;
                int nn = p >> 1;
                vv[u] = (p & 1) ? (-eh[nn] * powi[nn][i + 1]) : (eh[nn] * powr[nn][i + 1]);
            }
        }
        Pc[d] = pk2(vv[0], vv[1]);
    }
    // W rows: 64 bf16 = 32 dwords; 1024 dwords
    unsigned int* Wc = Ww + c * 1024;
    for (int kk = 0; kk < 16; ++kk) {
        int d = kk * 64 + t;
        int p = d >> 5;
        int j0 = (d & 31) * 2;
        int nn = p >> 1;
        float v0 = (p & 1) ? powi[nn][63 - j0] : powr[nn][63 - j0];
        float v1 = (p & 1) ? powi[nn][62 - j0] : powr[nn][62 - j0];
        Wc[d] = pk2(v0, v1);
    }
    if (t < 32) qw[c * 32 + t] = (t & 1) ? powi[t >> 1][64] : powr[t >> 1][64];
}

// LDS: XT0 8192 | XT1 8192 | S f32 [32][65] 8320 | SinT bf16 swizzled 4096
#define XT0_OFF 0
#define XT1_OFF 8192
#define S_OFF   16384
#define SIN_OFF 24704
#define SMEM_SZ 28800

__global__ __launch_bounds__(256) void conv_k(const float* __restrict__ x,
                                              const char* __restrict__ Pb,
                                              const char* __restrict__ Wb,
                                              const float* __restrict__ qw,
                                              float* __restrict__ y) {
    __shared__ __align__(16) char smem[SMEM_SZ];
    const int tid  = threadIdx.x;
    const int w    = tid >> 6, lane = tid & 63;
    const int g    = lane >> 4, l15 = lane & 15;
    const int bid  = blockIdx.x;
    const int c    = bid & (CH - 1);
    const int qq   = bid >> 10;                       // 0..7 -> rows b=2qq, 2qq+1
    const size_t roff0 = ((size_t)(2 * qq) * CH + c) * (size_t)LSEQ;
    const size_t roff1 = roff0 + (size_t)CH * LSEQ;

    // ---- prefetch A-fragments + q (L2-resident per XCD) ----
    const char* Pc = Pb + (size_t)c * 12288;
    const char* Wc = Wb + (size_t)c * 4096;
    short8 wa[2], pa[3];
    {
        int p = 16 * (w >> 1) + l15;
#pragma unroll
        for (int kt = 0; kt < 2; ++kt)
            wa[kt] = *(const short8*)(Wc + p * 128 + kt * 64 + g * 16);
        int i = 16 * w + l15;
#pragma unroll
        for (int kt = 0; kt < 3; ++kt)
            pa[kt] = *(const short8*)(Pc + i * 192 + kt * 64 + g * 16);
    }
    float qr0[4], qi0[4];
#pragma unroll
    for (int k = 0; k < 4; ++k) {
        int nn = 4 * w + k;
        qr0[k] = qw[c * 32 + 2 * nn];
        qi0[k] = qw[c * 32 + 2 * nn + 1];
    }

    // ---- issue BOTH rows' global loads up front ----
    float4 v0[4], v1[4];
#pragma unroll
    for (int it = 0; it < 4; ++it) v0[it] = *(const float4*)(x + roff0 + 1024 * it + 4 * tid);
#pragma unroll
    for (int it = 0; it < 4; ++it) v1[it] = *(const float4*)(x + roff1 + 1024 * it + 4 * tid);

    // ---- stage row0 -> XT0 (bf16, transposed, XOR-swizzled) ----
#pragma unroll
    for (int it = 0; it < 4; ++it) {
        int m = 16 * it + (tid >> 4);
        int byte = (m * 128 + 8 * (tid & 15)) ^ ((m & 7) << 4);
        *(uint2*)(smem + XT0_OFF + byte) = make_uint2(pk2(v0[it].x, v0[it].y), pk2(v0[it].z, v0[it].w));
    }
    __syncthreads();

    float* S = (float*)(smem + S_OFF);

    auto gemm1 = [&](int xoff) {
        f32x4 acc[2] = {{0.f, 0.f, 0.f, 0.f}, {0.f, 0.f, 0.f, 0.f}};
        int ntb = 2 * (w & 1);
#pragma unroll
        for (int nt = 0; nt < 2; ++nt) {
            int m = l15 + 16 * (ntb + nt);
            int sw = (m & 7) << 4;
#pragma unroll
            for (int kt = 0; kt < 2; ++kt) {
                short8 bf = *(const short8*)(smem + xoff + ((m * 128 + kt * 64 + g * 16) ^ sw));
                acc[nt] = __builtin_amdgcn_mfma_f32_16x16x32_bf16(wa[kt], bf, acc[nt], 0, 0, 0);
            }
        }
        int pbase = 16 * (w >> 1) + 4 * g;
#pragma unroll
        for (int nt = 0; nt < 2; ++nt) {
            int m = l15 + 16 * (ntb + nt);
#pragma unroll
            for (int r = 0; r < 4; ++r)
                S[(pbase + r) * 65 + m] = acc[nt][r];
        }
    };

    auto scan = [&]() {
        float sr[4], si[4], qr[4], qi[4];
#pragma unroll
        for (int k = 0; k < 4; ++k) {
            int nn = 4 * w + k;
            sr[k] = S[(2 * nn) * 65 + lane];
            si[k] = S[(2 * nn + 1) * 65 + lane];
            qr[k] = qr0[k];
            qi[k] = qi0[k];
        }
#pragma unroll
        for (int d = 1; d < 64; d <<= 1) {
#pragma unroll
            for (int k = 0; k < 4; ++k) {
                float ur = __shfl_up(sr[k], d);
                float ui = __shfl_up(si[k], d);
                ur = (lane >= d) ? ur : 0.f;
                ui = (lane >= d) ? ui : 0.f;
                sr[k] = fmaf(qr[k], ur, fmaf(-qi[k], ui, sr[k]));
                si[k] = fmaf(qr[k], ui, fmaf(qi[k], ur, si[k]));
            }
#pragma unroll
            for (int k = 0; k < 4; ++k) {   // q <- q^2
                float tq = fmaf(qr[k], qr[k], -(qi[k] * qi[k]));
                qi[k] = 2.f * qr[k] * qi[k];
                qr[k] = tq;
            }
        }
        unsigned int dw[4];
#pragma unroll
        for (int k = 0; k < 4; ++k) {       // exclusive shift: S_in[m] = A[m-1]
            float ar = __shfl_up(sr[k], 1);
            float ai = __shfl_up(si[k], 1);
            ar = (lane > 0) ? ar : 0.f;
            ai = (lane > 0) ? ai : 0.f;
            dw[k] = pk2(ar, ai);
        }
        int byte = (lane * 64 + 16 * w) ^ ((lane & 3) << 4);
        *(uint4*)(smem + SIN_OFF + byte) = make_uint4(dw[0], dw[1], dw[2], dw[3]);
    };

    auto gemm2 = [&](int xoff, float* yr) {
        f32x4 acc[4] = {{0.f,0.f,0.f,0.f},{0.f,0.f,0.f,0.f},{0.f,0.f,0.f,0.f},{0.f,0.f,0.f,0.f}};
#pragma unroll
        for (int nt = 0; nt < 4; ++nt) {
            int m = l15 + 16 * nt;
            int sw = (m & 7) << 4;
#pragma unroll
            for (int kt = 0; kt < 2; ++kt) {
                short8 bf = *(const short8*)(smem + xoff + ((m * 128 + kt * 64 + g * 16) ^ sw));
                acc[nt] = __builtin_amdgcn_mfma_f32_16x16x32_bf16(pa[kt], bf, acc[nt], 0, 0, 0);
            }
            short8 sf = *(const short8*)(smem + SIN_OFF + ((m * 64 + g * 16) ^ ((m & 3) << 4)));
            acc[nt] = __builtin_amdgcn_mfma_f32_16x16x32_bf16(pa[2], sf, acc[nt], 0, 0, 0);
        }
#pragma unroll
        for (int nt = 0; nt < 4; ++nt) {
            int m = l15 + 16 * nt;
            float4 v = make_float4(acc[nt][0], acc[nt][1], acc[nt][2], acc[nt][3]);
            *(float4*)(yr + m * 64 + 16 * w + 4 * g) = v;
        }
    };

    // ---- row0 pipeline, row1 staged in the gaps ----
    gemm1(XT0_OFF);
    __syncthreads();
    scan();
    // stage row1 -> XT1 (waits only on v1; overlaps with other waves' scan)
#pragma unroll
    for (int it = 0; it < 4; ++it) {
        int m = 16 * it + (tid >> 4);
        int byte = (m * 128 + 8 * (tid & 15)) ^ ((m & 7) << 4);
        *(uint2*)(smem + XT1_OFF + byte) = make_uint2(pk2(v1[it].x, v1[it].y), pk2(v1[it].z, v1[it].w));
    }
    __syncthreads();                       // Sin(0) + XT1 ready
    gemm2(XT0_OFF, y + roff0);             // y0 store fire-and-forget
    gemm1(XT1_OFF);                        // S(0) fully consumed before this barrier group
    __syncthreads();                       // S(1) ready; all gemm2(0) Sin-reads done
    scan();
    __syncthreads();                       // Sin(1) ready
    gemm2(XT1_OFF, y + roff1);
}

extern "C" void kernel_launch(void* const* d_in, const int* in_sizes, int n_in,
                              void* d_out, int out_size, void* d_ws, size_t ws_size,
                              hipStream_t stream) {
    const float* x      = (const float*)d_in[0];
    const float* A      = (const float*)d_in[1];
    const float* log_dt = (const float*)d_in[4];
    const float* E      = (const float*)d_in[5];
    float* out = (float*)d_out;
    char*  ws  = (char*)d_ws;

    unsigned int* Pw = (unsigned int*)ws;
    unsigned int* Ww = (unsigned int*)(ws + P_BYTES);
    float*        qw = (float*)(ws + P_BYTES + W_BYTES);

    setup_k<<<CH, 64, 0, stream>>>(A, log_dt, E, Pw, Ww, qw);
    conv_k<<<(BSZ / 2) * CH, 256, 0, stream>>>(x, (const char*)Pw, (const char*)Ww, qw, out);
}

// Round 7
// 130.983 us; speedup vs baseline: 1.8957x; 1.0057x over previous
//
#include <hip/hip_runtime.h>

#define CH   1024
#define BSZ  16
#define LSEQ 4096
#define NST  16

typedef __attribute__((ext_vector_type(8))) short short8;
typedef __attribute__((ext_vector_type(4))) float f32x4;

// pack two floats to bf16 pair (RNE), low = a, high = b
__device__ __forceinline__ unsigned int pk2(float a, float b) {
    unsigned int ua = __float_as_uint(a);
    unsigned int ub = __float_as_uint(b);
    ua = (ua + 0x7fffu + ((ua >> 16) & 1u)) >> 16;
    ub = (ub + 0x7fffu + ((ub >> 16) & 1u)) & 0xffff0000u;
    return ua | ub;
}

// ws byte layout:
//   P: [c][64 rows i][96 cols k] bf16   (K Toeplitz | D inject)   12,582,912 B
//   W: [c][32 rows p][64 cols j] bf16   (state extraction)         4,194,304 B
//   q: [c][32] f32   (lam^64 re,im interleaved)                      131,072 B
#define P_BYTES 12582912
#define W_BYTES 4194304

__global__ __launch_bounds__(64) void setup_k(const float* __restrict__ A,
                                              const float* __restrict__ log_dt,
                                              const float* __restrict__ E,
                                              unsigned int* __restrict__ Pw,
                                              unsigned int* __restrict__ Ww,
                                              float* __restrict__ qw) {
    __shared__ float powr[NST][65], powi[NST][65], eh[NST], klds[64];
    const int t = threadIdx.x, c = blockIdx.x;
    const int n = t & 15;
    const int idx = c * NST + n;
    float a0 = A[2 * idx], a1 = A[2 * idx + 1];
    float sp = (a0 > 20.f) ? a0 : log1pf(expf(a0));   // softplus
    float dt = expf(log_dt[idx]);
    float dar = -dt * sp, dai = dt * a1;
    float ehv = E[idx] * dt;
    if (t < NST) eh[t] = ehv;
    for (int l = t >> 4; l < 65; l += 4) {
        float mg = expf(dar * (float)l);
        float s, cs;
        sincosf(dai * (float)l, &s, &cs);
        powr[n][l] = mg * cs;
        powi[n][l] = mg * s;
    }
    __syncthreads();
    float kl = 0.f;
#pragma unroll
    for (int nn = 0; nn < NST; ++nn) kl += eh[nn] * powr[nn][t];
    klds[t] = kl;
    __syncthreads();
    // P rows: 96 bf16 = 48 dwords; 3072 dwords total, coalesced dword writes
    unsigned int* Pc = Pw + c * 3072;
    for (int kk = 0; kk < 48; ++kk) {
        int d = kk * 64 + t;
        int i = d / 48;
        int k0 = (d - i * 48) * 2;
        float vv[2];
#pragma unroll
        for (int u = 0; u < 2; ++u) {
            int k = k0 + u;
            if (k < 64) vv[u] = (k <= i) ? klds[i - k] : 0.f;
            else {
                int p = k - 64;
                int nn = p >> 1;
                vv[u] = (p & 1) ? (-eh[nn] * powi[nn][i + 1]) : (eh[nn] * powr[nn][i + 1]);
            }
        }
        Pc[d] = pk2(vv[0], vv[1]);
    }
    // W rows: 64 bf16 = 32 dwords; 1024 dwords
    unsigned int* Wc = Ww + c * 1024;
    for (int kk = 0; kk < 16; ++kk) {
        int d = kk * 64 + t;
        int p = d >> 5;
        int j0 = (d & 31) * 2;
        int nn = p >> 1;
        float v0 = (p & 1) ? powi[nn][63 - j0] : powr[nn][63 - j0];
        float v1 = (p & 1) ? powi[nn][62 - j0] : powr[nn][62 - j0];
        Wc[d] = pk2(v0, v1);
    }
    if (t < 32) qw[c * 32 + t] = (t & 1) ? powi[t >> 1][64] : powr[t >> 1][64];
}

// LDS: XT0 8192 | XT1 8192 | S f32 [32][65] 8320 | SinT bf16 swizzled 4096
#define XT0_OFF 0
#define XT1_OFF 8192
#define S_OFF   16384
#define SIN_OFF 24704
#define SMEM_SZ 28800

__global__ __launch_bounds__(256) void conv_k(const float* __restrict__ x,
                                              const char* __restrict__ Pb,
                                              const char* __restrict__ Wb,
                                              const float* __restrict__ qw,
                                              float* __restrict__ y) {
    __shared__ __align__(16) char smem[SMEM_SZ];
    const int tid  = threadIdx.x;
    const int w    = tid >> 6, lane = tid & 63;
    const int g    = lane >> 4, l15 = lane & 15;
    const int c    = blockIdx.x;            // persistent per channel

    // ---- params, loaded once per block (L2-resident per XCD) ----
    const char* Pc = Pb + (size_t)c * 12288;
    const char* Wc = Wb + (size_t)c * 4096;
    short8 wa[2], pa[3];
    {
        int p = 16 * (w >> 1) + l15;
#pragma unroll
        for (int kt = 0; kt < 2; ++kt)
            wa[kt] = *(const short8*)(Wc + p * 128 + kt * 64 + g * 16);
        int i = 16 * w + l15;
#pragma unroll
        for (int kt = 0; kt < 3; ++kt)
            pa[kt] = *(const short8*)(Pc + i * 192 + kt * 64 + g * 16);
    }
    float qr0[4], qi0[4];
#pragma unroll
    for (int k = 0; k < 4; ++k) {
        int nn = 4 * w + k;
        qr0[k] = qw[c * 32 + 2 * nn];
        qi0[k] = qw[c * 32 + 2 * nn + 1];
    }

    float* S = (float*)(smem + S_OFF);

    // staging-address precompute
    const int st_m    = tid >> 4;                       // +16*it
    const int st_base = 8 * (tid & 15);

    auto stage = [&](int xoff, const float4* v) {
#pragma unroll
        for (int it = 0; it < 4; ++it) {
            int m = 16 * it + st_m;
            int byte = (m * 128 + st_base) ^ ((m & 7) << 4);
            *(uint2*)(smem + xoff + byte) =
                make_uint2(pk2(v[it].x, v[it].y), pk2(v[it].z, v[it].w));
        }
    };

    auto gemm1 = [&](int xoff) {
        f32x4 acc[2] = {{0.f, 0.f, 0.f, 0.f}, {0.f, 0.f, 0.f, 0.f}};
        int ntb = 2 * (w & 1);
#pragma unroll
        for (int nt = 0; nt < 2; ++nt) {
            int m = l15 + 16 * (ntb + nt);
            int sw = (m & 7) << 4;
#pragma unroll
            for (int kt = 0; kt < 2; ++kt) {
                short8 bf = *(const short8*)(smem + xoff + ((m * 128 + kt * 64 + g * 16) ^ sw));
                acc[nt] = __builtin_amdgcn_mfma_f32_16x16x32_bf16(wa[kt], bf, acc[nt], 0, 0, 0);
            }
        }
        int pbase = 16 * (w >> 1) + 4 * g;
#pragma unroll
        for (int nt = 0; nt < 2; ++nt) {
            int m = l15 + 16 * (ntb + nt);
#pragma unroll
            for (int r = 0; r < 4; ++r)
                S[(pbase + r) * 65 + m] = acc[nt][r];
        }
    };

    auto scan = [&]() {
        float sr[4], si[4], qr[4], qi[4];
#pragma unroll
        for (int k = 0; k < 4; ++k) {
            int nn = 4 * w + k;
            sr[k] = S[(2 * nn) * 65 + lane];
            si[k] = S[(2 * nn + 1) * 65 + lane];
            qr[k] = qr0[k];
            qi[k] = qi0[k];
        }
#pragma unroll
        for (int d = 1; d < 64; d <<= 1) {
#pragma unroll
            for (int k = 0; k < 4; ++k) {
                float ur = __shfl_up(sr[k], d);
                float ui = __shfl_up(si[k], d);
                ur = (lane >= d) ? ur : 0.f;
                ui = (lane >= d) ? ui : 0.f;
                sr[k] = fmaf(qr[k], ur, fmaf(-qi[k], ui, sr[k]));
                si[k] = fmaf(qr[k], ui, fmaf(qi[k], ur, si[k]));
            }
#pragma unroll
            for (int k = 0; k < 4; ++k) {   // q <- q^2
                float tq = fmaf(qr[k], qr[k], -(qi[k] * qi[k]));
                qi[k] = 2.f * qr[k] * qi[k];
                qr[k] = tq;
            }
        }
        unsigned int dw[4];
#pragma unroll
        for (int k = 0; k < 4; ++k) {       // exclusive shift: S_in[m] = A[m-1]
            float ar = __shfl_up(sr[k], 1);
            float ai = __shfl_up(si[k], 1);
            ar = (lane > 0) ? ar : 0.f;
            ai = (lane > 0) ? ai : 0.f;
            dw[k] = pk2(ar, ai);
        }
        int byte = (lane * 64 + 16 * w) ^ ((lane & 3) << 4);
        *(uint4*)(smem + SIN_OFF + byte) = make_uint4(dw[0], dw[1], dw[2], dw[3]);
    };

    auto gemm2 = [&](int xoff, float* yr) {
        f32x4 acc[4] = {{0.f,0.f,0.f,0.f},{0.f,0.f,0.f,0.f},{0.f,0.f,0.f,0.f},{0.f,0.f,0.f,0.f}};
#pragma unroll
        for (int nt = 0; nt < 4; ++nt) {
            int m = l15 + 16 * nt;
            int sw = (m & 7) << 4;
#pragma unroll
            for (int kt = 0; kt < 2; ++kt) {
                short8 bf = *(const short8*)(smem + xoff + ((m * 128 + kt * 64 + g * 16) ^ sw));
                acc[nt] = __builtin_amdgcn_mfma_f32_16x16x32_bf16(pa[kt], bf, acc[nt], 0, 0, 0);
            }
            short8 sf = *(const short8*)(smem + SIN_OFF + ((m * 64 + g * 16) ^ ((m & 3) << 4)));
            acc[nt] = __builtin_amdgcn_mfma_f32_16x16x32_bf16(pa[2], sf, acc[nt], 0, 0, 0);
        }
#pragma unroll
        for (int nt = 0; nt < 4; ++nt) {
            int m = l15 + 16 * nt;
            float4 v = make_float4(acc[nt][0], acc[nt][1], acc[nt][2], acc[nt][3]);
            *(float4*)(yr + m * 64 + 16 * w + 4 * g) = v;
        }
    };

    // ---- persistent loop over all 16 batches, double-buffered XT ----
    const size_t cstride = (size_t)CH * LSEQ;
    const float* xr = x + (size_t)c * LSEQ + 4 * tid;
    float*       yb = y + (size_t)c * LSEQ;

    float4 v[4];
#pragma unroll
    for (int it = 0; it < 4; ++it) v[it] = *(const float4*)(xr + 1024 * it);   // row 0
    stage(XT0_OFF, v);
#pragma unroll
    for (int it = 0; it < 4; ++it) v[it] = *(const float4*)(xr + cstride + 1024 * it); // row 1
    __syncthreads();                         // XT0 ready

    int cur = 0;
    for (int b = 0; b < BSZ; ++b) {
        const int xoff = cur ? XT1_OFF : XT0_OFF;
        const int noff = cur ? XT0_OFF : XT1_OFF;
        gemm1(xoff);
        __syncthreads();                     // S ready; prev gemm2 LDS reads drained
        scan();
        if (b < BSZ - 1) {
            stage(noff, v);                  // consumes v (row b+1)
            if (b < BSZ - 2) {
                const float* xn = xr + (size_t)(b + 2) * cstride;
#pragma unroll
                for (int it = 0; it < 4; ++it) v[it] = *(const float4*)(xn + 1024 * it);
            }
        }
        __syncthreads();                     // Sin + XT[next] ready
        gemm2(xoff, yb + (size_t)b * cstride);
        cur ^= 1;
    }
}

extern "C" void kernel_launch(void* const* d_in, const int* in_sizes, int n_in,
                              void* d_out, int out_size, void* d_ws, size_t ws_size,
                              hipStream_t stream) {
    const float* x      = (const float*)d_in[0];
    const float* A      = (const float*)d_in[1];
    const float* log_dt = (const float*)d_in[4];
    const float* E      = (const float*)d_in[5];
    float* out = (float*)d_out;
    char*  ws  = (char*)d_ws;

    unsigned int* Pw = (unsigned int*)ws;
    unsigned int* Ww = (unsigned int*)(ws + P_BYTES);
    float*        qw = (float*)(ws + P_BYTES + W_BYTES);

    setup_k<<<CH, 64, 0, stream>>>(A, log_dt, E, Pw, Ww, qw);
    conv_k<<<CH, 256, 0, stream>>>(x, (const char*)Pw, (const char*)Ww, qw, out);
}

// Round 8
// 127.107 us; speedup vs baseline: 1.9535x; 1.0305x over previous
//
#include <hip/hip_runtime.h>
#include <hip/hip_bf16.h>

#define CH   1024
#define BSZ  16
#define LSEQ 4096
#define NST  16

typedef __attribute__((ext_vector_type(8))) short short8;
typedef __attribute__((ext_vector_type(4))) float f32x4;

__device__ __forceinline__ unsigned int pk2(float a, float b) {
    unsigned int ua = __float_as_uint(a);
    unsigned int ub = __float_as_uint(b);
    ua = (ua + 0x7fffu + ((ua >> 16) & 1u)) >> 16;
    ub = (ub + 0x7fffu + ((ub >> 16) & 1u)) & 0xffff0000u;
    return ua | ub;
}
__device__ __forceinline__ unsigned int pkrn(float a, float b) {
    __hip_bfloat162 h = __float22bfloat162_rn(make_float2(a, b));
    unsigned int u;
    __builtin_memcpy(&u, &h, 4);
    return u;
}
__device__ __forceinline__ float rfl(float x) {
    return __int_as_float(__builtin_amdgcn_readfirstlane(__float_as_int(x)));
}
// row_shr:d within 16-lane rows, OOB lanes read 0
#define DSHR(x, d) __int_as_float(__builtin_amdgcn_update_dpp(0, __float_as_int(x), 0x110 + (d), 0xf, 0xf, true))
// masked broadcast (rows not in RM get 0)
#define DBC(x, ctrl, rm) __int_as_float(__builtin_amdgcn_update_dpp(0, __float_as_int(x), (ctrl), (rm), 0xf, true))

#define P_BYTES 12582912
#define W_BYTES 4194304

__global__ __launch_bounds__(64) void setup_k(const float* __restrict__ A,
                                              const float* __restrict__ log_dt,
                                              const float* __restrict__ E,
                                              unsigned int* __restrict__ Pw,
                                              unsigned int* __restrict__ Ww,
                                              float* __restrict__ qw) {
    __shared__ float powr[NST][65], powi[NST][65], eh[NST], klds[64];
    const int t = threadIdx.x, c = blockIdx.x;
    const int n = t & 15;
    const int idx = c * NST + n;
    float a0 = A[2 * idx], a1 = A[2 * idx + 1];
    float sp = (a0 > 20.f) ? a0 : log1pf(expf(a0));
    float dt = expf(log_dt[idx]);
    float dar = -dt * sp, dai = dt * a1;
    float ehv = E[idx] * dt;
    if (t < NST) eh[t] = ehv;
    for (int l = t >> 4; l < 65; l += 4) {
        float mg = expf(dar * (float)l);
        float s, cs;
        sincosf(dai * (float)l, &s, &cs);
        powr[n][l] = mg * cs;
        powi[n][l] = mg * s;
    }
    __syncthreads();
    float kl = 0.f;
#pragma unroll
    for (int nn = 0; nn < NST; ++nn) kl += eh[nn] * powr[nn][t];
    klds[t] = kl;
    __syncthreads();
    unsigned int* Pc = Pw + c * 3072;
    for (int kk = 0; kk < 48; ++kk) {
        int d = kk * 64 + t;
        int i = d / 48;
        int k0 = (d - i * 48) * 2;
        float vv[2];
#pragma unroll
        for (int u = 0; u < 2; ++u) {
            int k = k0 + u;
            if (k < 64) vv[u] = (k <= i) ? klds[i - k] : 0.f;
            else {
                int p = k - 64;
                int nn = p >> 1;
                vv[u] = (p & 1) ? (-eh[nn] * powi[nn][i + 1]) : (eh[nn] * powr[nn][i + 1]);
            }
        }
        Pc[d] = pk2(vv[0], vv[1]);
    }
    unsigned int* Wc = Ww + c * 1024;
    for (int kk = 0; kk < 16; ++kk) {
        int d = kk * 64 + t;
        int p = d >> 5;
        int j0 = (d & 31) * 2;
        int nn = p >> 1;
        float v0 = (p & 1) ? powi[nn][63 - j0] : powr[nn][63 - j0];
        float v1 = (p & 1) ? powi[nn][62 - j0] : powr[nn][62 - j0];
        Wc[d] = pk2(v0, v1);
    }
    if (t < 32) qw[c * 32 + t] = (t & 1) ? powi[t >> 1][64] : powr[t >> 1][64];
}

#define XT0_OFF 0
#define XT1_OFF 8192
#define S_OFF   16384
#define SIN_OFF 24704
#define SMEM_SZ 28800

__global__ __launch_bounds__(256, 4) void conv_k(const float* __restrict__ x,
                                                 const char* __restrict__ Pb,
                                                 const char* __restrict__ Wb,
                                                 const float* __restrict__ qw,
                                                 float* __restrict__ y) {
    __shared__ __align__(16) char smem[SMEM_SZ];
    const int tid  = threadIdx.x;
    const int w    = tid >> 6, lane = tid & 63;
    const int g    = lane >> 4, l15 = lane & 15;
    const int c    = blockIdx.x;

    // ---- params (registers, once per block) ----
    const char* Pc = Pb + (size_t)c * 12288;
    const char* Wc = Wb + (size_t)c * 4096;
    short8 wa[2], pa[3];
    {
        int p = 16 * (w >> 1) + l15;
#pragma unroll
        for (int kt = 0; kt < 2; ++kt)
            wa[kt] = *(const short8*)(Wc + p * 128 + kt * 64 + g * 16);
        int i = 16 * w + l15;
#pragma unroll
        for (int kt = 0; kt < 3; ++kt)
            pa[kt] = *(const short8*)(Pc + i * 192 + kt * 64 + g * 16);
    }

    // ---- q powers (wave-uniform -> SGPR) + per-lane carry factors f,h ----
    float q1r[4], q1i[4], q2r[4], q2i[4], q4r[4], q4i[4], q8r[4], q8i[4];
    float fr[4], fi[4], hr[4], hi[4];
#pragma unroll
    for (int k = 0; k < 4; ++k) {
        int nn = 4 * w + k;
        float ar = qw[c * 32 + 2 * nn], ai = qw[c * 32 + 2 * nn + 1];
        float b2r = fmaf(ar, ar, -(ai * ai)), b2i = 2.f * ar * ai;
        float b4r = fmaf(b2r, b2r, -(b2i * b2i)), b4i = 2.f * b2r * b2i;
        float b8r = fmaf(b4r, b4r, -(b4i * b4i)), b8i = 2.f * b4r * b4i;
        float b16r = fmaf(b8r, b8r, -(b8i * b8i)), b16i = 2.f * b8r * b8i;
        q1r[k] = rfl(ar);  q1i[k] = rfl(ai);
        q2r[k] = rfl(b2r); q2i[k] = rfl(b2i);
        q4r[k] = rfl(b4r); q4i[k] = rfl(b4i);
        q8r[k] = rfl(b8r); q8i[k] = rfl(b8i);
        // f = q^(l15+1)
        float cr = ar, ci = ai;
        {
            float tr = fmaf(cr, ar, -(ci * ai)), ti = fmaf(cr, ai, ci * ar);
            cr = (l15 & 1) ? tr : cr; ci = (l15 & 1) ? ti : ci;
        }
        {
            float tr = fmaf(cr, b2r, -(ci * b2i)), ti = fmaf(cr, b2i, ci * b2r);
            cr = (l15 & 2) ? tr : cr; ci = (l15 & 2) ? ti : ci;
        }
        {
            float tr = fmaf(cr, b4r, -(ci * b4i)), ti = fmaf(cr, b4i, ci * b4r);
            cr = (l15 & 4) ? tr : cr; ci = (l15 & 4) ? ti : ci;
        }
        {
            float tr = fmaf(cr, b8r, -(ci * b8i)), ti = fmaf(cr, b8i, ci * b8r);
            cr = (l15 & 8) ? tr : cr; ci = (l15 & 8) ? ti : ci;
        }
        fr[k] = cr; fi[k] = ci;
        float tr = fmaf(cr, b16r, -(ci * b16i)), ti = fmaf(cr, b16i, ci * b16r);
        bool r3 = (lane >= 48);
        hr[k] = r3 ? tr : cr; hi[k] = r3 ? ti : ci;
    }

    // ---- precomputed addresses ----
    int xfo[4][2], sino[4], stb[2];
#pragma unroll
    for (int nt = 0; nt < 4; ++nt) {
#pragma unroll
        for (int kt = 0; kt < 2; ++kt)
            xfo[nt][kt] = ((l15 * 128 + kt * 64 + g * 16) ^ ((l15 & 7) << 4)) + nt * 2048;
        sino[nt] = ((l15 * 64 + g * 16) ^ ((l15 & 3) << 4)) + nt * 1024;
    }
#pragma unroll
    for (int it = 0; it < 2; ++it) {
        int slot = it * 256 + tid;
        int m = slot >> 3, js = slot & 7;
        stb[it] = (m * 128 + js * 16) ^ ((m & 7) << 4);
    }
    const int ntb  = (w & 1) << 1;                      // 0 or 2
    const int swb  = ((16 * (w >> 1) + 4 * g) * 65 + l15 + 16 * ntb) * 4;  // S write base (m = l15+16*ntb)
    const int srb  = (8 * w * 65 + lane) * 4;           // S read base
    const int sinw = (lane * 64 + 16 * w) ^ ((lane & 3) << 4);

    float* Sf = (float*)(smem + S_OFF);
    (void)Sf;

    short8 xf[4][2];
    auto rdfrags = [&](int xoff) {
#pragma unroll
        for (int nt = 0; nt < 4; ++nt)
#pragma unroll
            for (int kt = 0; kt < 2; ++kt)
                xf[nt][kt] = *(const short8*)(smem + xoff + xfo[nt][kt]);
    };

    auto gemm1 = [&]() {
        f32x4 a0 = {0.f, 0.f, 0.f, 0.f}, a1 = {0.f, 0.f, 0.f, 0.f};
        if ((w & 1) == 0) {
#pragma unroll
            for (int kt = 0; kt < 2; ++kt) {
                a0 = __builtin_amdgcn_mfma_f32_16x16x32_bf16(wa[kt], xf[0][kt], a0, 0, 0, 0);
                a1 = __builtin_amdgcn_mfma_f32_16x16x32_bf16(wa[kt], xf[1][kt], a1, 0, 0, 0);
            }
        } else {
#pragma unroll
            for (int kt = 0; kt < 2; ++kt) {
                a0 = __builtin_amdgcn_mfma_f32_16x16x32_bf16(wa[kt], xf[2][kt], a0, 0, 0, 0);
                a1 = __builtin_amdgcn_mfma_f32_16x16x32_bf16(wa[kt], xf[3][kt], a1, 0, 0, 0);
            }
        }
#pragma unroll
        for (int r = 0; r < 4; ++r) {
            *(float*)(smem + S_OFF + swb + r * 260)      = a0[r];
            *(float*)(smem + S_OFF + swb + r * 260 + 64) = a1[r];
        }
    };

    auto scan = [&]() {
        float sr[4], si[4];
#pragma unroll
        for (int k = 0; k < 4; ++k) {
            sr[k] = *(const float*)(smem + S_OFF + srb + k * 520);
            si[k] = *(const float*)(smem + S_OFF + srb + k * 520 + 260);
        }
        // in-row weighted scan (DPP, zero-fill at row edges)
#pragma unroll
        for (int k = 0; k < 4; ++k) {
            { float ur = DSHR(sr[k], 1), ui = DSHR(si[k], 1);
              sr[k] = fmaf(q1r[k], ur, fmaf(-q1i[k], ui, sr[k]));
              si[k] = fmaf(q1r[k], ui, fmaf(q1i[k], ur, si[k])); }
            { float ur = DSHR(sr[k], 2), ui = DSHR(si[k], 2);
              sr[k] = fmaf(q2r[k], ur, fmaf(-q2i[k], ui, sr[k]));
              si[k] = fmaf(q2r[k], ui, fmaf(q2i[k], ur, si[k])); }
            { float ur = DSHR(sr[k], 4), ui = DSHR(si[k], 4);
              sr[k] = fmaf(q4r[k], ur, fmaf(-q4i[k], ui, sr[k]));
              si[k] = fmaf(q4r[k], ui, fmaf(q4i[k], ur, si[k])); }
            { float ur = DSHR(sr[k], 8), ui = DSHR(si[k], 8);
              sr[k] = fmaf(q8r[k], ur, fmaf(-q8i[k], ui, sr[k]));
              si[k] = fmaf(q8r[k], ui, fmaf(q8i[k], ur, si[k])); }
            // cross-row carry: rows 1,3 <- prev row total (bcast15), rows 2,3 <- lane31 (bcast31)
            { float ur = DBC(sr[k], 0x142, 0xa), ui = DBC(si[k], 0x142, 0xa);
              sr[k] = fmaf(fr[k], ur, fmaf(-fi[k], ui, sr[k]));
              si[k] = fmaf(fr[k], ui, fmaf(fi[k], ur, si[k])); }
            { float ur = DBC(sr[k], 0x143, 0xc), ui = DBC(si[k], 0x143, 0xc);
              sr[k] = fmaf(hr[k], ur, fmaf(-hi[k], ui, sr[k]));
              si[k] = fmaf(hr[k], ui, fmaf(hi[k], ur, si[k])); }
        }
        // exclusive shift + pack to bf16
        unsigned int dw[4];
#pragma unroll
        for (int k = 0; k < 4; ++k) {
            float ar = __shfl_up(sr[k], 1);
            float ai = __shfl_up(si[k], 1);
            ar = (lane > 0) ? ar : 0.f;
            ai = (lane > 0) ? ai : 0.f;
            dw[k] = pkrn(ar, ai);
        }
        *(uint4*)(smem + SIN_OFF + sinw) = make_uint4(dw[0], dw[1], dw[2], dw[3]);
    };

    auto gemm2 = [&](float* yr) {
        f32x4 acc[4] = {{0.f,0.f,0.f,0.f},{0.f,0.f,0.f,0.f},{0.f,0.f,0.f,0.f},{0.f,0.f,0.f,0.f}};
#pragma unroll
        for (int nt = 0; nt < 4; ++nt) {
            acc[nt] = __builtin_amdgcn_mfma_f32_16x16x32_bf16(pa[0], xf[nt][0], acc[nt], 0, 0, 0);
            short8 sf = *(const short8*)(smem + SIN_OFF + sino[nt]);
            acc[nt] = __builtin_amdgcn_mfma_f32_16x16x32_bf16(pa[2], sf, acc[nt], 0, 0, 0);
        }
        if (w >= 2) {   // Toeplitz rows <32 have all-zero k in [32,64)
#pragma unroll
            for (int nt = 0; nt < 4; ++nt)
                acc[nt] = __builtin_amdgcn_mfma_f32_16x16x32_bf16(pa[1], xf[nt][1], acc[nt], 0, 0, 0);
        }
#pragma unroll
        for (int nt = 0; nt < 4; ++nt) {
            int m = l15 + 16 * nt;
            float4 v = make_float4(acc[nt][0], acc[nt][1], acc[nt][2], acc[nt][3]);
            *(float4*)(yr + m * 64 + 16 * w + 4 * g) = v;
        }
    };

    float4 pend[4];
    const float* xr = x + (size_t)c * LSEQ;
    float*       yb = y + (size_t)c * LSEQ;
    const size_t cstride = (size_t)CH * LSEQ;

    auto ldraw = [&](const float* xp) {
#pragma unroll
        for (int it = 0; it < 2; ++it) {
            int slot = it * 256 + tid;
            pend[2 * it]     = *(const float4*)(xp + slot * 8);
            pend[2 * it + 1] = *(const float4*)(xp + slot * 8 + 4);
        }
    };
    auto stage = [&](int xoff) {
#pragma unroll
        for (int it = 0; it < 2; ++it) {
            uint4 pk;
            pk.x = pkrn(pend[2 * it].x,     pend[2 * it].y);
            pk.y = pkrn(pend[2 * it].z,     pend[2 * it].w);
            pk.z = pkrn(pend[2 * it + 1].x, pend[2 * it + 1].y);
            pk.w = pkrn(pend[2 * it + 1].z, pend[2 * it + 1].w);
            *(uint4*)(smem + xoff + stb[it]) = pk;
        }
    };

    // ---- prologue ----
    ldraw(xr);
    stage(XT0_OFF);
    ldraw(xr + cstride);
    __syncthreads();

#pragma unroll 1
    for (int bb = 0; bb < 8; ++bb) {
        // phase A: row 2bb from XT0; stage row 2bb+1 -> XT1; load row 2bb+2
        rdfrags(XT0_OFF);
        gemm1();
        __syncthreads();
        scan();
        stage(XT1_OFF);
        if (bb < 7) ldraw(xr + (size_t)(2 * bb + 2) * cstride);
        __syncthreads();
        gemm2(yb + (size_t)(2 * bb) * cstride);

        // phase B: row 2bb+1 from XT1; stage row 2bb+2 -> XT0; load row 2bb+3
        rdfrags(XT1_OFF);
        gemm1();
        __syncthreads();
        scan();
        if (bb < 7) {
            stage(XT0_OFF);
            ldraw(xr + (size_t)(2 * bb + 3) * cstride);
        }
        __syncthreads();
        gemm2(yb + (size_t)(2 * bb + 1) * cstride);
    }
}

extern "C" void kernel_launch(void* const* d_in, const int* in_sizes, int n_in,
                              void* d_out, int out_size, void* d_ws, size_t ws_size,
                              hipStream_t stream) {
    const float* x      = (const float*)d_in[0];
    const float* A      = (const float*)d_in[1];
    const float* log_dt = (const float*)d_in[4];
    const float* E      = (const float*)d_in[5];
    float* out = (float*)d_out;
    char*  ws  = (char*)d_ws;

    unsigned int* Pw = (unsigned int*)ws;
    unsigned int* Ww = (unsigned int*)(ws + P_BYTES);
    float*        qw = (float*)(ws + P_BYTES + W_BYTES);

    setup_k<<<CH, 64, 0, stream>>>(A, log_dt, E, Pw, Ww, qw);
    conv_k<<<CH, 256, 0, stream>>>(x, (const char*)Pw, (const char*)Ww, qw, out);
}

// Round 9
// 110.660 us; speedup vs baseline: 2.2438x; 1.1486x over previous
//
#include <hip/hip_runtime.h>
#include <hip/hip_bf16.h>

#define CH   1024
#define BSZ  16
#define LSEQ 4096
#define NST  16

typedef __attribute__((ext_vector_type(8))) short short8;
typedef __attribute__((ext_vector_type(4))) float f32x4;

__device__ __forceinline__ unsigned int pkrn(float a, float b) {
    __hip_bfloat162 h = __float22bfloat162_rn(make_float2(a, b));
    unsigned int u;
    __builtin_memcpy(&u, &h, 4);
    return u;
}
__device__ __forceinline__ float rfl(float x) {
    return __int_as_float(__builtin_amdgcn_readfirstlane(__float_as_int(x)));
}
// row_shr:d within 16-lane rows, OOB lanes read 0
#define DSHR(x, d) __int_as_float(__builtin_amdgcn_update_dpp(0, __float_as_int(x), 0x110 + (d), 0xf, 0xf, true))
// masked broadcast (rows not in RM get 0)
#define DBC(x, ctrl, rm) __int_as_float(__builtin_amdgcn_update_dpp(0, __float_as_int(x), (ctrl), (rm), 0xf, true))

#define XT0_OFF 0
#define XT1_OFF 8192
#define S_OFF   16384
#define SIN_OFF 24704
#define SMEM_SZ 28800

// barrier that drains ONLY lgkmcnt (LDS) — y-stores/x-loads stay in flight
__device__ __forceinline__ void barrier_fast() {
    asm volatile("s_waitcnt lgkmcnt(0)\n\ts_barrier" ::: "memory");
}

__global__ __launch_bounds__(256, 4) void conv_k(const float* __restrict__ x,
                                                 const float* __restrict__ A,
                                                 const float* __restrict__ log_dt,
                                                 const float* __restrict__ E,
                                                 float* __restrict__ y) {
    __shared__ __align__(16) char smem[SMEM_SZ];
    const int tid  = threadIdx.x;
    const int w    = tid >> 6, lane = tid & 63;
    const int g    = lane >> 4, l15 = lane & 15;
    const int bid  = blockIdx.x;
    const int c    = bid >> 1;
    const int half = bid & 1;                 // batches 8*half .. 8*half+7

    const size_t cstride = (size_t)CH * LSEQ;
    const float* xr = x + ((size_t)(8 * half) * CH + c) * (size_t)LSEQ;
    float*       yb = y + ((size_t)(8 * half) * CH + c) * (size_t)LSEQ;

    // ---- staging addresses ----
    int stb[2];
#pragma unroll
    for (int it = 0; it < 2; ++it) {
        int slot = it * 256 + tid;
        int m = slot >> 3, js = slot & 7;
        stb[it] = (m * 128 + js * 16) ^ ((m & 7) << 4);
    }
    float4 pend[4];
    auto ldraw = [&](const float* xp) {
#pragma unroll
        for (int it = 0; it < 2; ++it) {
            int slot = it * 256 + tid;
            pend[2 * it]     = *(const float4*)(xp + slot * 8);
            pend[2 * it + 1] = *(const float4*)(xp + slot * 8 + 4);
        }
    };
    auto stage = [&](int xoff) {
#pragma unroll
        for (int it = 0; it < 2; ++it) {
            uint4 pk;
            pk.x = pkrn(pend[2 * it].x,     pend[2 * it].y);
            pk.y = pkrn(pend[2 * it].z,     pend[2 * it].w);
            pk.z = pkrn(pend[2 * it + 1].x, pend[2 * it + 1].y);
            pk.w = pkrn(pend[2 * it + 1].z, pend[2 * it + 1].w);
            *(uint4*)(smem + xoff + stb[it]) = pk;
        }
    };

    ldraw(xr);                                 // row 0: issue ASAP, hides under prologue

    // ---- fused setup: lambda-power tables in LDS (S/SIN regions, freed before main loop) ----
    float* PR = (float*)(smem + S_OFF);        // [16][65]
    float* PI = PR + NST * 65;                 // [16][65]
    float* EH = (float*)(smem + SIN_OFF);      // [16]
    float* KL = EH + NST;                      // [64]
    {
        int n = tid & 15;
        int idx0 = c * NST + n;
        float a0 = A[2 * idx0], a1 = A[2 * idx0 + 1];
        float sp = (a0 > 20.f) ? a0 : log1pf(expf(a0));   // softplus
        float dtv = expf(log_dt[idx0]);
        float dar = -dtv * sp, dai = dtv * a1;
        if (tid < NST) EH[tid] = E[idx0] * dtv;
        for (int l = tid >> 4; l < 65; l += 16) {
            float mg = expf(dar * (float)l);
            float s, cs;
            sincosf(dai * (float)l, &s, &cs);
            PR[n * 65 + l] = mg * cs;
            PI[n * 65 + l] = mg * s;
        }
    }
    __syncthreads();
    if (tid < 64) {
        float kl = 0.f;
#pragma unroll
        for (int nn = 0; nn < NST; ++nn) kl += EH[nn] * PR[nn * 65 + tid];
        KL[tid] = kl;
    }
    __syncthreads();

    // ---- assemble MFMA fragments from LDS tables ----
    short8 wa[2], pa[3];
    {
        int p = 16 * (w >> 1) + l15;
        const float* tb = ((p & 1) ? PI : PR) + (p >> 1) * 65;
#pragma unroll
        for (int kt = 0; kt < 2; ++kt) {
            union { short8 v; unsigned int d[4]; } u;
#pragma unroll
            for (int e2 = 0; e2 < 4; ++e2) {
                int j = kt * 32 + 8 * g + 2 * e2;
                u.d[e2] = pkrn(tb[63 - j], tb[62 - j]);
            }
            wa[kt] = u.v;
        }
        int i = 16 * w + l15;
#pragma unroll
        for (int kt = 0; kt < 2; ++kt) {
            union { short8 v; unsigned int d[4]; } u;
#pragma unroll
            for (int e2 = 0; e2 < 4; ++e2) {
                int k0 = kt * 32 + 8 * g + 2 * e2;
                float v0 = (k0 <= i)     ? KL[i - k0]     : 0.f;
                float v1 = (k0 + 1 <= i) ? KL[i - k0 - 1] : 0.f;
                u.d[e2] = pkrn(v0, v1);
            }
            pa[kt] = u.v;
        }
        {
            union { short8 v; unsigned int d[4]; } u;
#pragma unroll
            for (int e2 = 0; e2 < 4; ++e2) {
                int n3 = 4 * g + e2;
                float re = EH[n3] * PR[n3 * 65 + i + 1];
                float im = -EH[n3] * PI[n3 * 65 + i + 1];
                u.d[e2] = pkrn(re, im);
            }
            pa[2] = u.v;
        }
    }

    // ---- q powers (wave-uniform -> SGPR) + per-lane carry factors f,h ----
    float q1r[4], q1i[4], q2r[4], q2i[4], q4r[4], q4i[4], q8r[4], q8i[4];
    float fr[4], fi[4], hr[4], hi[4];
#pragma unroll
    for (int k = 0; k < 4; ++k) {
        int nn = 4 * w + k;
        float ar = PR[nn * 65 + 64], ai = PI[nn * 65 + 64];
        float b2r = fmaf(ar, ar, -(ai * ai)), b2i = 2.f * ar * ai;
        float b4r = fmaf(b2r, b2r, -(b2i * b2i)), b4i = 2.f * b2r * b2i;
        float b8r = fmaf(b4r, b4r, -(b4i * b4i)), b8i = 2.f * b4r * b4i;
        float b16r = fmaf(b8r, b8r, -(b8i * b8i)), b16i = 2.f * b8r * b8i;
        q1r[k] = rfl(ar);  q1i[k] = rfl(ai);
        q2r[k] = rfl(b2r); q2i[k] = rfl(b2i);
        q4r[k] = rfl(b4r); q4i[k] = rfl(b4i);
        q8r[k] = rfl(b8r); q8i[k] = rfl(b8i);
        float cr = ar, ci = ai;
        {
            float tr = fmaf(cr, ar, -(ci * ai)), ti = fmaf(cr, ai, ci * ar);
            cr = (l15 & 1) ? tr : cr; ci = (l15 & 1) ? ti : ci;
        }
        {
            float tr = fmaf(cr, b2r, -(ci * b2i)), ti = fmaf(cr, b2i, ci * b2r);
            cr = (l15 & 2) ? tr : cr; ci = (l15 & 2) ? ti : ci;
        }
        {
            float tr = fmaf(cr, b4r, -(ci * b4i)), ti = fmaf(cr, b4i, ci * b4r);
            cr = (l15 & 4) ? tr : cr; ci = (l15 & 4) ? ti : ci;
        }
        {
            float tr = fmaf(cr, b8r, -(ci * b8i)), ti = fmaf(cr, b8i, ci * b8r);
            cr = (l15 & 8) ? tr : cr; ci = (l15 & 8) ? ti : ci;
        }
        fr[k] = cr; fi[k] = ci;
        float tr = fmaf(cr, b16r, -(ci * b16i)), ti = fmaf(cr, b16i, ci * b16r);
        bool r3 = (lane >= 48);
        hr[k] = r3 ? tr : cr; hi[k] = r3 ? ti : ci;
    }

    // ---- precomputed main-loop addresses ----
    int xfo[4][2], sino[4];
#pragma unroll
    for (int nt = 0; nt < 4; ++nt) {
#pragma unroll
        for (int kt = 0; kt < 2; ++kt)
            xfo[nt][kt] = ((l15 * 128 + kt * 64 + g * 16) ^ ((l15 & 7) << 4)) + nt * 2048;
        sino[nt] = ((l15 * 64 + g * 16) ^ ((l15 & 3) << 4)) + nt * 1024;
    }
    const int ntb  = (w & 1) << 1;
    const int swb  = ((16 * (w >> 1) + 4 * g) * 65 + l15 + 16 * ntb) * 4;
    const int srb  = (8 * w * 65 + lane) * 4;
    const int sinw = (lane * 64 + 16 * w) ^ ((lane & 3) << 4);

    short8 xf[4][2];
    auto rdfrags = [&](int xoff) {
#pragma unroll
        for (int nt = 0; nt < 4; ++nt)
#pragma unroll
            for (int kt = 0; kt < 2; ++kt)
                xf[nt][kt] = *(const short8*)(smem + xoff + xfo[nt][kt]);
    };

    auto gemm1 = [&]() {
        f32x4 a0 = {0.f, 0.f, 0.f, 0.f}, a1 = {0.f, 0.f, 0.f, 0.f};
        if ((w & 1) == 0) {
#pragma unroll
            for (int kt = 0; kt < 2; ++kt) {
                a0 = __builtin_amdgcn_mfma_f32_16x16x32_bf16(wa[kt], xf[0][kt], a0, 0, 0, 0);
                a1 = __builtin_amdgcn_mfma_f32_16x16x32_bf16(wa[kt], xf[1][kt], a1, 0, 0, 0);
            }
        } else {
#pragma unroll
            for (int kt = 0; kt < 2; ++kt) {
                a0 = __builtin_amdgcn_mfma_f32_16x16x32_bf16(wa[kt], xf[2][kt], a0, 0, 0, 0);
                a1 = __builtin_amdgcn_mfma_f32_16x16x32_bf16(wa[kt], xf[3][kt], a1, 0, 0, 0);
            }
        }
#pragma unroll
        for (int r = 0; r < 4; ++r) {
            *(float*)(smem + S_OFF + swb + r * 260)      = a0[r];
            *(float*)(smem + S_OFF + swb + r * 260 + 64) = a1[r];
        }
    };

    auto scan = [&]() {
        float sr[4], si[4];
#pragma unroll
        for (int k = 0; k < 4; ++k) {
            sr[k] = *(const float*)(smem + S_OFF + srb + k * 520);
            si[k] = *(const float*)(smem + S_OFF + srb + k * 520 + 260);
        }
#pragma unroll
        for (int k = 0; k < 4; ++k) {
            { float ur = DSHR(sr[k], 1), ui = DSHR(si[k], 1);
              sr[k] = fmaf(q1r[k], ur, fmaf(-q1i[k], ui, sr[k]));
              si[k] = fmaf(q1r[k], ui, fmaf(q1i[k], ur, si[k])); }
            { float ur = DSHR(sr[k], 2), ui = DSHR(si[k], 2);
              sr[k] = fmaf(q2r[k], ur, fmaf(-q2i[k], ui, sr[k]));
              si[k] = fmaf(q2r[k], ui, fmaf(q2i[k], ur, si[k])); }
            { float ur = DSHR(sr[k], 4), ui = DSHR(si[k], 4);
              sr[k] = fmaf(q4r[k], ur, fmaf(-q4i[k], ui, sr[k]));
              si[k] = fmaf(q4r[k], ui, fmaf(q4i[k], ur, si[k])); }
            { float ur = DSHR(sr[k], 8), ui = DSHR(si[k], 8);
              sr[k] = fmaf(q8r[k], ur, fmaf(-q8i[k], ui, sr[k]));
              si[k] = fmaf(q8r[k], ui, fmaf(q8i[k], ur, si[k])); }
            { float ur = DBC(sr[k], 0x142, 0xa), ui = DBC(si[k], 0x142, 0xa);
              sr[k] = fmaf(fr[k], ur, fmaf(-fi[k], ui, sr[k]));
              si[k] = fmaf(fr[k], ui, fmaf(fi[k], ur, si[k])); }
            { float ur = DBC(sr[k], 0x143, 0xc), ui = DBC(si[k], 0x143, 0xc);
              sr[k] = fmaf(hr[k], ur, fmaf(-hi[k], ui, sr[k]));
              si[k] = fmaf(hr[k], ui, fmaf(hi[k], ur, si[k])); }
        }
        unsigned int dw[4];
#pragma unroll
        for (int k = 0; k < 4; ++k) {
            float ar = __shfl_up(sr[k], 1);
            float ai = __shfl_up(si[k], 1);
            ar = (lane > 0) ? ar : 0.f;
            ai = (lane > 0) ? ai : 0.f;
            dw[k] = pkrn(ar, ai);
        }
        *(uint4*)(smem + SIN_OFF + sinw) = make_uint4(dw[0], dw[1], dw[2], dw[3]);
    };

    auto gemm2 = [&](float* yr) {
        f32x4 acc[4] = {{0.f,0.f,0.f,0.f},{0.f,0.f,0.f,0.f},{0.f,0.f,0.f,0.f},{0.f,0.f,0.f,0.f}};
#pragma unroll
        for (int nt = 0; nt < 4; ++nt) {
            acc[nt] = __builtin_amdgcn_mfma_f32_16x16x32_bf16(pa[0], xf[nt][0], acc[nt], 0, 0, 0);
            short8 sf = *(const short8*)(smem + SIN_OFF + sino[nt]);
            acc[nt] = __builtin_amdgcn_mfma_f32_16x16x32_bf16(pa[2], sf, acc[nt], 0, 0, 0);
        }
        if (w >= 2) {
#pragma unroll
            for (int nt = 0; nt < 4; ++nt)
                acc[nt] = __builtin_amdgcn_mfma_f32_16x16x32_bf16(pa[1], xf[nt][1], acc[nt], 0, 0, 0);
        }
#pragma unroll
        for (int nt = 0; nt < 4; ++nt) {
            int m = l15 + 16 * nt;
            float4 v = make_float4(acc[nt][0], acc[nt][1], acc[nt][2], acc[nt][3]);
            *(float4*)(yr + m * 64 + 16 * w + 4 * g) = v;
        }
    };

    // ---- prologue staging (tables consumed; safe to overwrite after barrier) ----
    stage(XT0_OFF);
    ldraw(xr + cstride);
    __syncthreads();

#pragma unroll 1
    for (int bb = 0; bb < 4; ++bb) {
        // phase A: row 2bb from XT0
        rdfrags(XT0_OFF);
        gemm1();
        barrier_fast();
        scan();
        stage(XT1_OFF);
        if (bb < 3) ldraw(xr + (size_t)(2 * bb + 2) * cstride);
        barrier_fast();
        gemm2(yb + (size_t)(2 * bb) * cstride);

        // phase B: row 2bb+1 from XT1
        rdfrags(XT1_OFF);
        gemm1();
        barrier_fast();
        scan();
        if (bb < 3) {
            stage(XT0_OFF);
            ldraw(xr + (size_t)(2 * bb + 3) * cstride);
        }
        barrier_fast();
        gemm2(yb + (size_t)(2 * bb + 1) * cstride);
    }
}

extern "C" void kernel_launch(void* const* d_in, const int* in_sizes, int n_in,
                              void* d_out, int out_size, void* d_ws, size_t ws_size,
                              hipStream_t stream) {
    const float* x      = (const float*)d_in[0];
    const float* A      = (const float*)d_in[1];
    const float* log_dt = (const float*)d_in[4];
    const float* E      = (const float*)d_in[5];
    float* out = (float*)d_out;
    (void)d_ws; (void)ws_size;

    conv_k<<<2 * CH, 256, 0, stream>>>(x, A, log_dt, E, out);
}

// Round 10
// 109.969 us; speedup vs baseline: 2.2579x; 1.0063x over previous
//
#include <hip/hip_runtime.h>
#include <hip/hip_bf16.h>

#define CH   1024
#define BSZ  16
#define LSEQ 4096
#define NST  16

typedef __attribute__((ext_vector_type(8))) short short8;
typedef __attribute__((ext_vector_type(4))) float f32x4;

__device__ __forceinline__ unsigned int pkrn(float a, float b) {
    __hip_bfloat162 h = __float22bfloat162_rn(make_float2(a, b));
    unsigned int u;
    __builtin_memcpy(&u, &h, 4);
    return u;
}
__device__ __forceinline__ float rfl(float x) {
    return __int_as_float(__builtin_amdgcn_readfirstlane(__float_as_int(x)));
}
// row_shr:d within 16-lane rows, OOB lanes read 0
#define DSHR(x, d) __int_as_float(__builtin_amdgcn_update_dpp(0, __float_as_int(x), 0x110 + (d), 0xf, 0xf, true))
// masked broadcast (rows not in RM get 0)
#define DBC(x, ctrl, rm) __int_as_float(__builtin_amdgcn_update_dpp(0, __float_as_int(x), (ctrl), (rm), 0xf, true))

#define XT0_OFF 0
#define XT1_OFF 8192
#define S_OFF   16384
#define SIN_OFF 24704
#define SMEM_SZ 28800

// barrier that drains ONLY lgkmcnt (LDS) — y-stores/x-loads stay in flight
__device__ __forceinline__ void barrier_fast() {
    asm volatile("s_waitcnt lgkmcnt(0)\n\ts_barrier" ::: "memory");
}

__global__ __launch_bounds__(256, 4) void conv_k(const float* __restrict__ x,
                                                 const float* __restrict__ A,
                                                 const float* __restrict__ log_dt,
                                                 const float* __restrict__ E,
                                                 float* __restrict__ y) {
    __shared__ __align__(16) char smem[SMEM_SZ];
    const int tid  = threadIdx.x;
    const int w    = tid >> 6, lane = tid & 63;
    const int g    = lane >> 4, l15 = lane & 15;
    const int bid  = blockIdx.x;
    const int c    = bid >> 1;
    const int half = bid & 1;                 // batches 8*half .. 8*half+7

    const size_t cstride = (size_t)CH * LSEQ;
    const float* xr = x + ((size_t)(8 * half) * CH + c) * (size_t)LSEQ;
    float*       yb = y + ((size_t)(8 * half) * CH + c) * (size_t)LSEQ;

    // ---- staging addresses ----
    int stb[2];
#pragma unroll
    for (int it = 0; it < 2; ++it) {
        int slot = it * 256 + tid;
        int m = slot >> 3, js = slot & 7;
        stb[it] = (m * 128 + js * 16) ^ ((m & 7) << 4);
    }
    float4 pend[4];
    auto ldraw = [&](const float* xp) {
#pragma unroll
        for (int it = 0; it < 2; ++it) {
            int slot = it * 256 + tid;
            pend[2 * it]     = *(const float4*)(xp + slot * 8);
            pend[2 * it + 1] = *(const float4*)(xp + slot * 8 + 4);
        }
    };
    auto stage = [&](int xoff) {
#pragma unroll
        for (int it = 0; it < 2; ++it) {
            uint4 pk;
            pk.x = pkrn(pend[2 * it].x,     pend[2 * it].y);
            pk.y = pkrn(pend[2 * it].z,     pend[2 * it].w);
            pk.z = pkrn(pend[2 * it + 1].x, pend[2 * it + 1].y);
            pk.w = pkrn(pend[2 * it + 1].z, pend[2 * it + 1].w);
            *(uint4*)(smem + xoff + stb[it]) = pk;
        }
    };

    ldraw(xr);                                 // row 0: issue ASAP, hides under prologue

    // ---- fused setup: lambda-power tables in LDS (S/SIN regions, freed before main loop) ----
    float* PR = (float*)(smem + S_OFF);        // [16][65]
    float* PI = PR + NST * 65;                 // [16][65]
    float* EH = (float*)(smem + SIN_OFF);      // [16]
    float* KL = EH + NST;                      // [64]
    {
        int n = tid & 15;
        int idx0 = c * NST + n;
        float a0 = A[2 * idx0], a1 = A[2 * idx0 + 1];
        float sp = (a0 > 20.f) ? a0 : log1pf(expf(a0));   // softplus
        float dtv = expf(log_dt[idx0]);
        float dar = -dtv * sp, dai = dtv * a1;
        if (tid < NST) EH[tid] = E[idx0] * dtv;
        for (int l = tid >> 4; l < 65; l += 16) {
            float mg = expf(dar * (float)l);
            float s, cs;
            sincosf(dai * (float)l, &s, &cs);
            PR[n * 65 + l] = mg * cs;
            PI[n * 65 + l] = mg * s;
        }
    }
    __syncthreads();
    if (tid < 64) {
        float kl = 0.f;
#pragma unroll
        for (int nn = 0; nn < NST; ++nn) kl += EH[nn] * PR[nn * 65 + tid];
        KL[tid] = kl;
    }
    __syncthreads();

    // ---- assemble MFMA fragments from LDS tables ----
    short8 wa[2], pa[3];
    {
        int p = 16 * (w >> 1) + l15;
        const float* tb = ((p & 1) ? PI : PR) + (p >> 1) * 65;
#pragma unroll
        for (int kt = 0; kt < 2; ++kt) {
            union { short8 v; unsigned int d[4]; } u;
#pragma unroll
            for (int e2 = 0; e2 < 4; ++e2) {
                int j = kt * 32 + 8 * g + 2 * e2;
                u.d[e2] = pkrn(tb[63 - j], tb[62 - j]);
            }
            wa[kt] = u.v;
        }
        int i = 16 * w + l15;
#pragma unroll
        for (int kt = 0; kt < 2; ++kt) {
            union { short8 v; unsigned int d[4]; } u;
#pragma unroll
            for (int e2 = 0; e2 < 4; ++e2) {
                int k0 = kt * 32 + 8 * g + 2 * e2;
                float v0 = (k0 <= i)     ? KL[i - k0]     : 0.f;
                float v1 = (k0 + 1 <= i) ? KL[i - k0 - 1] : 0.f;
                u.d[e2] = pkrn(v0, v1);
            }
            pa[kt] = u.v;
        }
        {
            union { short8 v; unsigned int d[4]; } u;
#pragma unroll
            for (int e2 = 0; e2 < 4; ++e2) {
                int n3 = 4 * g + e2;
                float re = EH[n3] * PR[n3 * 65 + i + 1];
                float im = -EH[n3] * PI[n3 * 65 + i + 1];
                u.d[e2] = pkrn(re, im);
            }
            pa[2] = u.v;
        }
    }

    // ---- q powers (wave-uniform -> SGPR) + per-lane carry factors f,h ----
    float q1r[4], q1i[4], q2r[4], q2i[4], q4r[4], q4i[4], q8r[4], q8i[4];
    float fr[4], fi[4], hr[4], hi[4];
#pragma unroll
    for (int k = 0; k < 4; ++k) {
        int nn = 4 * w + k;
        float ar = PR[nn * 65 + 64], ai = PI[nn * 65 + 64];
        float b2r = fmaf(ar, ar, -(ai * ai)), b2i = 2.f * ar * ai;
        float b4r = fmaf(b2r, b2r, -(b2i * b2i)), b4i = 2.f * b2r * b2i;
        float b8r = fmaf(b4r, b4r, -(b4i * b4i)), b8i = 2.f * b4r * b4i;
        float b16r = fmaf(b8r, b8r, -(b8i * b8i)), b16i = 2.f * b8r * b8i;
        q1r[k] = rfl(ar);  q1i[k] = rfl(ai);
        q2r[k] = rfl(b2r); q2i[k] = rfl(b2i);
        q4r[k] = rfl(b4r); q4i[k] = rfl(b4i);
        q8r[k] = rfl(b8r); q8i[k] = rfl(b8i);
        float cr = ar, ci = ai;
        {
            float tr = fmaf(cr, ar, -(ci * ai)), ti = fmaf(cr, ai, ci * ar);
            cr = (l15 & 1) ? tr : cr; ci = (l15 & 1) ? ti : ci;
        }
        {
            float tr = fmaf(cr, b2r, -(ci * b2i)), ti = fmaf(cr, b2i, ci * b2r);
            cr = (l15 & 2) ? tr : cr; ci = (l15 & 2) ? ti : ci;
        }
        {
            float tr = fmaf(cr, b4r, -(ci * b4i)), ti = fmaf(cr, b4i, ci * b4r);
            cr = (l15 & 4) ? tr : cr; ci = (l15 & 4) ? ti : ci;
        }
        {
            float tr = fmaf(cr, b8r, -(ci * b8i)), ti = fmaf(cr, b8i, ci * b8r);
            cr = (l15 & 8) ? tr : cr; ci = (l15 & 8) ? ti : ci;
        }
        fr[k] = cr; fi[k] = ci;
        float tr = fmaf(cr, b16r, -(ci * b16i)), ti = fmaf(cr, b16i, ci * b16r);
        bool r3 = (lane >= 48);
        hr[k] = r3 ? tr : cr; hi[k] = r3 ? ti : ci;
    }

    // ---- precomputed main-loop addresses ----
    int xfo[4][2], sino[4];
#pragma unroll
    for (int nt = 0; nt < 4; ++nt) {
#pragma unroll
        for (int kt = 0; kt < 2; ++kt)
            xfo[nt][kt] = ((l15 * 128 + kt * 64 + g * 16) ^ ((l15 & 7) << 4)) + nt * 2048;
        sino[nt] = ((l15 * 64 + g * 16) ^ ((l15 & 3) << 4)) + nt * 1024;
    }
    const int ntb  = (w & 1) << 1;
    const int swb  = ((16 * (w >> 1) + 4 * g) * 65 + l15 + 16 * ntb) * 4;
    const int srb  = (8 * w * 65 + lane) * 4;
    const int sinw = (lane * 64 + 16 * w) ^ ((lane & 3) << 4);

    short8 xf[4][2];
    auto rdfrags = [&](int xoff) {
#pragma unroll
        for (int nt = 0; nt < 4; ++nt)
#pragma unroll
            for (int kt = 0; kt < 2; ++kt)
                xf[nt][kt] = *(const short8*)(smem + xoff + xfo[nt][kt]);
    };

    auto gemm1 = [&]() {
        f32x4 a0 = {0.f, 0.f, 0.f, 0.f}, a1 = {0.f, 0.f, 0.f, 0.f};
        if ((w & 1) == 0) {
#pragma unroll
            for (int kt = 0; kt < 2; ++kt) {
                a0 = __builtin_amdgcn_mfma_f32_16x16x32_bf16(wa[kt], xf[0][kt], a0, 0, 0, 0);
                a1 = __builtin_amdgcn_mfma_f32_16x16x32_bf16(wa[kt], xf[1][kt], a1, 0, 0, 0);
            }
        } else {
#pragma unroll
            for (int kt = 0; kt < 2; ++kt) {
                a0 = __builtin_amdgcn_mfma_f32_16x16x32_bf16(wa[kt], xf[2][kt], a0, 0, 0, 0);
                a1 = __builtin_amdgcn_mfma_f32_16x16x32_bf16(wa[kt], xf[3][kt], a1, 0, 0, 0);
            }
        }
#pragma unroll
        for (int r = 0; r < 4; ++r) {
            *(float*)(smem + S_OFF + swb + r * 260)      = a0[r];
            *(float*)(smem + S_OFF + swb + r * 260 + 64) = a1[r];
        }
    };

    auto scan = [&]() {
        float sr[4], si[4];
#pragma unroll
        for (int k = 0; k < 4; ++k) {
            sr[k] = *(const float*)(smem + S_OFF + srb + k * 520);
            si[k] = *(const float*)(smem + S_OFF + srb + k * 520 + 260);
        }
#pragma unroll
        for (int k = 0; k < 4; ++k) {
            { float ur = DSHR(sr[k], 1), ui = DSHR(si[k], 1);
              sr[k] = fmaf(q1r[k], ur, fmaf(-q1i[k], ui, sr[k]));
              si[k] = fmaf(q1r[k], ui, fmaf(q1i[k], ur, si[k])); }
            { float ur = DSHR(sr[k], 2), ui = DSHR(si[k], 2);
              sr[k] = fmaf(q2r[k], ur, fmaf(-q2i[k], ui, sr[k]));
              si[k] = fmaf(q2r[k], ui, fmaf(q2i[k], ur, si[k])); }
            { float ur = DSHR(sr[k], 4), ui = DSHR(si[k], 4);
              sr[k] = fmaf(q4r[k], ur, fmaf(-q4i[k], ui, sr[k]));
              si[k] = fmaf(q4r[k], ui, fmaf(q4i[k], ur, si[k])); }
            { float ur = DSHR(sr[k], 8), ui = DSHR(si[k], 8);
              sr[k] = fmaf(q8r[k], ur, fmaf(-q8i[k], ui, sr[k]));
              si[k] = fmaf(q8r[k], ui, fmaf(q8i[k], ur, si[k])); }
            { float ur = DBC(sr[k], 0x142, 0xa), ui = DBC(si[k], 0x142, 0xa);
              sr[k] = fmaf(fr[k], ur, fmaf(-fi[k], ui, sr[k]));
              si[k] = fmaf(fr[k], ui, fmaf(fi[k], ur, si[k])); }
            { float ur = DBC(sr[k], 0x143, 0xc), ui = DBC(si[k], 0x143, 0xc);
              sr[k] = fmaf(hr[k], ur, fmaf(-hi[k], ui, sr[k]));
              si[k] = fmaf(hr[k], ui, fmaf(hi[k], ur, si[k])); }
        }
        unsigned int dw[4];
#pragma unroll
        for (int k = 0; k < 4; ++k) {
            float ar = __shfl_up(sr[k], 1);
            float ai = __shfl_up(si[k], 1);
            ar = (lane > 0) ? ar : 0.f;
            ai = (lane > 0) ? ai : 0.f;
            dw[k] = pkrn(ar, ai);
        }
        *(uint4*)(smem + SIN_OFF + sinw) = make_uint4(dw[0], dw[1], dw[2], dw[3]);
    };

    // ---- one full row: gemm2's X-part hoisted BEFORE bar1 (overlaps barrier wait);
    //      only scan sits between the barriers; SIN MFMA + store after bar2. ----
    auto row = [&](int xc, int xn, float* yr, const float* xpre, bool do_stage) {
        rdfrags(xc);
        gemm1();
        f32x4 acc[4];
#pragma unroll
        for (int nt = 0; nt < 4; ++nt) {
            f32x4 z = {0.f, 0.f, 0.f, 0.f};
            acc[nt] = __builtin_amdgcn_mfma_f32_16x16x32_bf16(pa[0], xf[nt][0], z, 0, 0, 0);
        }
        if (w >= 2) {
#pragma unroll
            for (int nt = 0; nt < 4; ++nt)
                acc[nt] = __builtin_amdgcn_mfma_f32_16x16x32_bf16(pa[1], xf[nt][1], acc[nt], 0, 0, 0);
        }
        // pin the hoisted MFMAs before the barrier (register-only ops can sink past asm)
        asm volatile("" :: "v"(acc[0]), "v"(acc[1]), "v"(acc[2]), "v"(acc[3]));
        if (do_stage) stage(xn);
        if (xpre) ldraw(xpre);
        barrier_fast();
        scan();
        barrier_fast();
#pragma unroll
        for (int nt = 0; nt < 4; ++nt) {
            short8 sf = *(const short8*)(smem + SIN_OFF + sino[nt]);
            acc[nt] = __builtin_amdgcn_mfma_f32_16x16x32_bf16(pa[2], sf, acc[nt], 0, 0, 0);
        }
#pragma unroll
        for (int nt = 0; nt < 4; ++nt) {
            int m = l15 + 16 * nt;
            float4 v = make_float4(acc[nt][0], acc[nt][1], acc[nt][2], acc[nt][3]);
            *(float4*)(yr + m * 64 + 16 * w + 4 * g) = v;
        }
    };

    // ---- prologue staging (tables consumed; safe to overwrite after barrier) ----
    stage(XT0_OFF);
    ldraw(xr + cstride);
    __syncthreads();

#pragma unroll 1
    for (int bb = 0; bb < 4; ++bb) {
        row(XT0_OFF, XT1_OFF, yb + (size_t)(2 * bb) * cstride,
            (bb < 3) ? (xr + (size_t)(2 * bb + 2) * cstride) : nullptr, true);
        row(XT1_OFF, XT0_OFF, yb + (size_t)(2 * bb + 1) * cstride,
            (bb < 3) ? (xr + (size_t)(2 * bb + 3) * cstride) : nullptr, bb < 3);
    }
}

extern "C" void kernel_launch(void* const* d_in, const int* in_sizes, int n_in,
                              void* d_out, int out_size, void* d_ws, size_t ws_size,
                              hipStream_t stream) {
    const float* x      = (const float*)d_in[0];
    const float* A      = (const float*)d_in[1];
    const float* log_dt = (const float*)d_in[4];
    const float* E      = (const float*)d_in[5];
    float* out = (float*)d_out;
    (void)d_ws; (void)ws_size;

    conv_k<<<2 * CH, 256, 0, stream>>>(x, A, log_dt, E, out);
}